// Round 3
// baseline (55626.086 us; speedup 1.0000x reference)
//
#include <hip/hip_runtime.h>

#define T_STEPS 4096
#define HD 512
#define G3HD 1536
#define NCODES 4880
#define NWG 32
#define FLAG_PAIR 0x0000000100000001ULL

typedef __attribute__((ext_vector_type(2))) float v2f;
typedef __attribute__((ext_vector_type(4))) unsigned uint4v;

// ---------------------------------------------------------------------------
// GEMM1: visit[4096][512] = H^T (4096x4880) @ X_emb (4880x512)
// ---------------------------------------------------------------------------
__global__ __launch_bounds__(256) void gemm1_kernel(const float* __restrict__ H,
                                                    const float* __restrict__ X,
                                                    float* __restrict__ C) {
  __shared__ float As[16][68];
  __shared__ float Bs[16][68];
  const int m0 = blockIdx.x * 64;
  const int n0 = blockIdx.y * 64;
  const int tid = threadIdx.x;
  const int lk = tid >> 4;
  const int lm = (tid & 15) << 2;
  const int tm = (tid & 15) << 2;
  const int tn = (tid >> 4) << 2;
  float acc[4][4] = {};
  for (int k0 = 0; k0 < NCODES; k0 += 16) {
    float4 av = *(const float4*)(H + (size_t)(k0 + lk) * T_STEPS + m0 + lm);
    float4 bv = *(const float4*)(X + (size_t)(k0 + lk) * HD + n0 + lm);
    __syncthreads();
    *(float4*)(&As[lk][lm]) = av;
    *(float4*)(&Bs[lk][lm]) = bv;
    __syncthreads();
#pragma unroll
    for (int kk = 0; kk < 16; ++kk) {
      float4 a = *(const float4*)(&As[kk][tm]);
      float4 b = *(const float4*)(&Bs[kk][tn]);
      float ar[4] = {a.x, a.y, a.z, a.w};
      float br[4] = {b.x, b.y, b.z, b.w};
#pragma unroll
      for (int i = 0; i < 4; ++i)
#pragma unroll
        for (int j = 0; j < 4; ++j) acc[i][j] += ar[i] * br[j];
    }
  }
#pragma unroll
  for (int i = 0; i < 4; ++i) {
    float4 o = make_float4(acc[i][0], acc[i][1], acc[i][2], acc[i][3]);
    *(float4*)(C + (size_t)(m0 + tm + i) * HD + n0 + tn) = o;
  }
}

// ---------------------------------------------------------------------------
// GEMM2: gi[4096][1536] = visit (4096x512) @ W_ih^T (512x1536) + b_ih
// ---------------------------------------------------------------------------
__global__ __launch_bounds__(256) void gemm2_kernel(const float* __restrict__ A,
                                                    const float* __restrict__ B,
                                                    const float* __restrict__ bias,
                                                    float* __restrict__ Cout) {
  __shared__ float As[16][68];
  __shared__ float Bs[16][68];
  const int m0 = blockIdx.x * 64;
  const int n0 = blockIdx.y * 64;
  const int tid = threadIdx.x;
  const int lr = tid >> 2;
  const int lkq = (tid & 3) << 2;
  const int tm = (tid & 15) << 2;
  const int tn = (tid >> 4) << 2;
  float acc[4][4] = {};
  for (int k0 = 0; k0 < HD; k0 += 16) {
    float4 av = *(const float4*)(A + (size_t)(m0 + lr) * HD + k0 + lkq);
    float4 bv = *(const float4*)(B + (size_t)(n0 + lr) * HD + k0 + lkq);
    __syncthreads();
    As[lkq + 0][lr] = av.x; As[lkq + 1][lr] = av.y;
    As[lkq + 2][lr] = av.z; As[lkq + 3][lr] = av.w;
    Bs[lkq + 0][lr] = bv.x; Bs[lkq + 1][lr] = bv.y;
    Bs[lkq + 2][lr] = bv.z; Bs[lkq + 3][lr] = bv.w;
    __syncthreads();
#pragma unroll
    for (int kk = 0; kk < 16; ++kk) {
      float4 a = *(const float4*)(&As[kk][tm]);
      float4 b = *(const float4*)(&Bs[kk][tn]);
      float ar[4] = {a.x, a.y, a.z, a.w};
      float br[4] = {b.x, b.y, b.z, b.w};
#pragma unroll
      for (int i = 0; i < 4; ++i)
#pragma unroll
        for (int j = 0; j < 4; ++j) acc[i][j] += ar[i] * br[j];
    }
  }
  const float b0 = bias[n0 + tn + 0];
  const float b1 = bias[n0 + tn + 1];
  const float b2 = bias[n0 + tn + 2];
  const float b3 = bias[n0 + tn + 3];
#pragma unroll
  for (int i = 0; i < 4; ++i) {
    float4 o = make_float4(acc[i][0] + b0, acc[i][1] + b1, acc[i][2] + b2, acc[i][3] + b3);
    *(float4*)(Cout + (size_t)(m0 + tm + i) * G3HD + n0 + tn) = o;
  }
}

// ---------------------------------------------------------------------------
// Persistent GRU scan, XCD-pinned team of 32 WGs x 256 thr. WG g owns h
// elements [16g,16g+16) and the 48 matching W_hh rows; 96 weight floats per
// lane in registers (AGPR-parked by the compiler).
// Exchange protocol (the round-2 fix): producers do 16 PLAIN h stores
// (wave 0, lanes 0..15) then ONE release-agent flag store (lane 0) -- the
// wave-level vmcnt(0) before the release covers all 16 lanes' stores.
// Consumers spin on ONE relaxed u64 atomic load covering both producer WGs
// of their 32-float chunk, then acquire-fence (L1 inv) + 8 PLAIN float4
// loads (pipelined under a single vmcnt). This removes the 16-serialized-
// atomic-load poll and the 1 MB/sweep redundant L2 traffic of round 2.
// ---------------------------------------------------------------------------
__global__ __launch_bounds__(256, 1) void scan_kernel(const float* __restrict__ gi,
                                                      const float* __restrict__ W_hh,
                                                      const float* __restrict__ b_hh,
                                                      float* __restrict__ hs,
                                                      int* __restrict__ flags,
                                                      int* __restrict__ ctrl) {
  __shared__ int s_role;
  __shared__ __align__(16) float gibuf[2][64][48];  // [buf][step&63][gate*16+elem]
  __shared__ float part[2][4][3][16];               // [t&1][wave][gate][elem]
  const int tid = threadIdx.x;

  if (tid == 0) {
    int xcd;
    asm volatile("s_getreg_b32 %0, hwreg(HW_REG_XCC_ID)" : "=s"(xcd));
    int role = -1;
    const int slot = atomicAdd(&ctrl[xcd], 1);
    if (slot < NWG) {
      if (slot == NWG - 1) atomicCAS(&ctrl[8], -1, xcd);
      int wnr;
      while ((wnr = __hip_atomic_load(&ctrl[8], __ATOMIC_RELAXED,
                                      __HIP_MEMORY_SCOPE_AGENT)) < 0) {
        __builtin_amdgcn_s_sleep(16);
      }
      if (wnr == xcd) role = slot;
    }
    s_role = role;
  }
  __syncthreads();
  const int g = s_role;
  if (g < 0) return;

  const int w = tid >> 6;        // wave 0..3 -> k range [128w, 128w+128)
  const int l = tid & 63;
  const int g2 = l >> 2;         // element-in-WG 0..15
  const int q = l & 3;           // k quarter -> 32-float chunk
  const int k0 = w * 128 + q * 32;
  const int e = g * 16 + g2;
  const int p0 = 8 * w + 2 * q;  // even producer-WG index of this chunk

  // 96 weight floats per lane, held in registers across the whole scan.
  v2f w2[3][16];
#pragma unroll
  for (int r = 0; r < 3; ++r) {
    const v2f* wp = (const v2f*)(W_hh + (size_t)(r * HD + e) * HD + k0);
#pragma unroll
    for (int j = 0; j < 16; ++j) w2[r][j] = wp[j];
  }
#pragma unroll
  for (int r = 0; r < 3; ++r)
#pragma unroll
    for (int j = 0; j < 16; ++j) asm volatile("" : "+v"(w2[r][j]));

  float bh_r = 0.f, bh_z = 0.f, bh_n = 0.f, hprev = 0.f;
  if (tid < 16) {
    const int ej = g * 16 + tid;
    bh_r = b_hh[ej];
    bh_z = b_hh[HD + ej];
    bh_n = b_hh[2 * HD + ej];
  }

  // Prologue: stage gi block 0 (rows 0..63) into gibuf[0].
  uint4v st[3];
#pragma unroll
  for (int j = 0; j < 3; ++j) {
    const int c = tid + 256 * j, row = c / 12, seg = c % 12;
    st[j] = *(const uint4v*)(gi + (size_t)row * G3HD + (seg >> 2) * HD + g * 16 + (seg & 3) * 4);
  }
#pragma unroll
  for (int j = 0; j < 3; ++j) {
    const int c = tid + 256 * j, row = c / 12, seg = c % 12;
    *(uint4v*)&gibuf[0][row][seg * 4] = st[j];
  }
  __syncthreads();

  for (int t = 0; t < T_STEPS; ++t) {
    const int pb = t & 1;
    const int cb = (t >> 6) & 1;
    const int ts = t & 63;

    // ---- wait for this lane's two producer WGs, then plain-load the chunk ----
    v2f h2[16];
    if (t == 0) {
#pragma unroll
      for (int m = 0; m < 16; ++m) h2[m] = (v2f)(0.f);  // h(-1) = 0
    } else {
      const unsigned long long* fp =
          (const unsigned long long*)(flags + (size_t)(t - 1) * NWG + p0);
      while (__hip_atomic_load(fp, __ATOMIC_RELAXED, __HIP_MEMORY_SCOPE_AGENT) !=
             FLAG_PAIR) {
      }
      __builtin_amdgcn_fence(__ATOMIC_ACQUIRE, "agent");
      const float4* hp = (const float4*)(hs + (size_t)(t - 1) * HD + k0);
      float4 f[8];
#pragma unroll
      for (int m = 0; m < 8; ++m) f[m] = hp[m];  // plain, pipelined
#pragma unroll
      for (int m = 0; m < 8; ++m) {
        h2[2 * m].x = f[m].x;
        h2[2 * m].y = f[m].y;
        h2[2 * m + 1].x = f[m].z;
        h2[2 * m + 1].y = f[m].w;
      }
    }

    // ---- gi LDS-write of previously issued block at ts==1 ----
    if (ts == 1 && t + 63 < T_STEPS) {
#pragma unroll
      for (int j = 0; j < 3; ++j) {
        const int c = tid + 256 * j, row = c / 12, seg = c % 12;
        *(uint4v*)&gibuf[cb ^ 1][row][seg * 4] = st[j];
      }
    }

    // ---- gate-lane gi reads for this step (latency hidden under matvec) ----
    float gir = 0.f, giz = 0.f, gin = 0.f;
    if (tid < 16) {
      gir = gibuf[cb][ts][tid];
      giz = gibuf[cb][ts][16 + tid];
      gin = gibuf[cb][ts][32 + tid];
    }

    // ---- matvec: 3 rows x 32 k per lane, 48 v_pk_fma_f32 ----
    v2f acc0 = (v2f)(0.f), acc1 = (v2f)(0.f), acc2 = (v2f)(0.f);
#pragma unroll
    for (int m = 0; m < 16; ++m) {
      acc0 = __builtin_elementwise_fma(w2[0][m], h2[m], acc0);
      acc1 = __builtin_elementwise_fma(w2[1][m], h2[m], acc1);
      acc2 = __builtin_elementwise_fma(w2[2][m], h2[m], acc2);
    }
    float s0 = acc0.x + acc0.y;
    float s1 = acc1.x + acc1.y;
    float s2 = acc2.x + acc2.y;
    s0 += __shfl_xor(s0, 1); s1 += __shfl_xor(s1, 1); s2 += __shfl_xor(s2, 1);
    s0 += __shfl_xor(s0, 2); s1 += __shfl_xor(s1, 2); s2 += __shfl_xor(s2, 2);
    if (q == 0) {
      part[pb][w][0][g2] = s0;
      part[pb][w][1][g2] = s1;
      part[pb][w][2][g2] = s2;
    }
    __syncthreads();  // the only barrier per step

    // ---- gates on 16 lanes (wave 0), then release-publish this WG's flag ----
    if (tid < 16) {
      float xr = part[pb][0][0][tid] + part[pb][1][0][tid] + part[pb][2][0][tid] + part[pb][3][0][tid];
      float xz = part[pb][0][1][tid] + part[pb][1][1][tid] + part[pb][2][1][tid] + part[pb][3][1][tid];
      float xn = part[pb][0][2][tid] + part[pb][1][2][tid] + part[pb][2][2][tid] + part[pb][3][2][tid];
      xr += gir + bh_r;
      xz += giz + bh_z;
      const float ghn = xn + bh_n;
      const float rr = __builtin_amdgcn_rcpf(1.f + __expf(-xr));
      const float zz = __builtin_amdgcn_rcpf(1.f + __expf(-xz));
      const float y = gin + rr * ghn;
      const float nn = 1.f - 2.f * __builtin_amdgcn_rcpf(__expf(2.f * y) + 1.f);
      const float hnew = nn + zz * (hprev - nn);
      hs[(size_t)t * HD + (g * 16 + tid)] = hnew;  // plain store; release covers it
      hprev = hnew;
      if (tid == 0)
        __hip_atomic_store(&flags[(size_t)t * NWG + g], 1, __ATOMIC_RELEASE,
                           __HIP_MEMORY_SCOPE_AGENT);
    }

    // ---- gi prefetch issue at ts==0 (after release: keeps vmcnt(0) clean) ----
    if (ts == 0 && t + 64 < T_STEPS) {
#pragma unroll
      for (int j = 0; j < 3; ++j) {
        const int c = tid + 256 * j, row = c / 12, seg = c % 12;
        st[j] = *(const uint4v*)(gi + (size_t)(t + 64 + row) * G3HD + (seg >> 2) * HD +
                                 g * 16 + (seg & 3) * 4);
      }
    }
  }
}

// ---------------------------------------------------------------------------
// logits[t] = hs[t] . w_att   (off the scan critical path)
// ---------------------------------------------------------------------------
__global__ __launch_bounds__(256) void logits_kernel(const float* __restrict__ hs,
                                                     const float* __restrict__ w_att,
                                                     float* __restrict__ logits) {
  const int tid = threadIdx.x;
  const int r = blockIdx.x * 32 + (tid >> 3);
  const int c0 = (tid & 7) * 64;
  const float4* hp = (const float4*)(hs + (size_t)r * HD + c0);
  const float4* wp = (const float4*)(w_att + c0);
  float acc = 0.f;
#pragma unroll
  for (int i = 0; i < 16; ++i) {
    float4 h4 = hp[i], w4 = wp[i];
    acc += h4.x * w4.x + h4.y * w4.y + h4.z * w4.z + h4.w * w4.w;
  }
  acc += __shfl_xor(acc, 1);
  acc += __shfl_xor(acc, 2);
  acc += __shfl_xor(acc, 4);
  if ((tid & 7) == 0) logits[r] = acc;
}

// ---------------------------------------------------------------------------
// Softmax over 4096 logits, write alpha; zero out.
// ---------------------------------------------------------------------------
__global__ __launch_bounds__(256) void softmax_kernel(const float* __restrict__ logits,
                                                      float* __restrict__ alpha,
                                                      float* __restrict__ out) {
  __shared__ float tmp[4];
  const int tid = threadIdx.x;
  float l[16];
  float m = -1e30f;
#pragma unroll
  for (int i = 0; i < 16; ++i) {
    l[i] = logits[i * 256 + tid];
    m = fmaxf(m, l[i]);
  }
#pragma unroll
  for (int o = 32; o > 0; o >>= 1) m = fmaxf(m, __shfl_xor(m, o));
  if ((tid & 63) == 0) tmp[tid >> 6] = m;
  __syncthreads();
  m = fmaxf(fmaxf(tmp[0], tmp[1]), fmaxf(tmp[2], tmp[3]));
  __syncthreads();
  float e[16];
  float s = 0.f;
#pragma unroll
  for (int i = 0; i < 16; ++i) {
    e[i] = expf(l[i] - m);
    s += e[i];
  }
#pragma unroll
  for (int o = 32; o > 0; o >>= 1) s += __shfl_xor(s, o);
  if ((tid & 63) == 0) tmp[tid >> 6] = s;
  __syncthreads();
  s = tmp[0] + tmp[1] + tmp[2] + tmp[3];
  const float inv = 1.f / s;
#pragma unroll
  for (int i = 0; i < 16; ++i) alpha[i * 256 + tid] = e[i] * inv;
  out[tid] = 0.f;
  out[256 + tid] = 0.f;
}

// ---------------------------------------------------------------------------
// out[j] = sum_t alpha[t] * hs[t][j].  128 WGs: 2 j-halves x 64 t-chunks.
// ---------------------------------------------------------------------------
__global__ __launch_bounds__(256) void wsum_kernel(const float* __restrict__ alpha,
                                                   const float* __restrict__ hs,
                                                   float* __restrict__ out) {
  const int tid = threadIdx.x;
  const int jblk = (blockIdx.x & 1) * 256;
  const int tc = blockIdx.x >> 1;
  float acc = 0.f;
  for (int tt = 0; tt < 64; ++tt) {
    const int t = tc * 64 + tt;
    acc += alpha[t] * hs[(size_t)t * HD + jblk + tid];
  }
  atomicAdd(&out[jblk + tid], acc);
}

extern "C" void kernel_launch(void* const* d_in, const int* in_sizes, int n_in,
                              void* d_out, int out_size, void* d_ws, size_t ws_size,
                              hipStream_t stream) {
  const float* H     = (const float*)d_in[0];
  // d_in[1] = TE, unused by the reference
  const float* X_emb = (const float*)d_in[2];
  const float* W_ih  = (const float*)d_in[3];
  const float* W_hh  = (const float*)d_in[4];
  const float* b_ih  = (const float*)d_in[5];
  const float* b_hh  = (const float*)d_in[6];
  const float* w_att = (const float*)d_in[7];
  float* out = (float*)d_out;

  char* ws = (char*)d_ws;
  float* visit  = (float*)(ws + 0);          //  8 MB: 4096x512 (dead after gemm2)
  int*   flags  = (int*)(ws + 0);            // 512 KB overlay; zeroed AFTER gemm2
  float* gi     = (float*)(ws + 8388608);    // 25 MB: 4096x1536
  float* hs     = (float*)(ws + 33554432);   //  8 MB: 4096x512
  float* logits = (float*)(ws + 41943040);   // 16 KB: 4096
  float* alpha  = (float*)(ws + 41959424);   // 16 KB
  int*   ctrl   = (int*)(ws + 41975808);     // [0..7] per-XCD counters, [8] winner

  hipMemsetAsync(ctrl, 0, 8 * sizeof(int), stream);
  hipMemsetAsync(ctrl + 8, 0xFF, sizeof(int), stream);  // winner = -1

  gemm1_kernel<<<dim3(64, 8), 256, 0, stream>>>(H, X_emb, visit);
  gemm2_kernel<<<dim3(64, 24), 256, 0, stream>>>(visit, W_ih, b_ih, gi);
  // visit is dead now; reuse its storage for the step-completion flags.
  hipMemsetAsync(flags, 0, (size_t)T_STEPS * NWG * sizeof(int), stream);
  scan_kernel<<<256, 256, 0, stream>>>(gi, W_hh, b_hh, hs, flags, ctrl);
  logits_kernel<<<128, 256, 0, stream>>>(hs, w_att, logits);
  softmax_kernel<<<1, 256, 0, stream>>>(logits, alpha, out);
  wsum_kernel<<<128, 256, 0, stream>>>(alpha, hs, out);
}

// Round 4
// 15588.951 us; speedup vs baseline: 3.5683x; 3.5683x over previous
//
#include <hip/hip_runtime.h>

#define T_STEPS 4096
#define HD 512
#define G3HD 1536
#define NCODES 4880
#define NWG 16
#define SENT 0xFFFFFFFFu

typedef __attribute__((ext_vector_type(2))) float v2f;
typedef __attribute__((ext_vector_type(4))) unsigned uint4v;

// ---------------------------------------------------------------------------
// GEMM1: visit[4096][512] = H^T (4096x4880) @ X_emb (4880x512)
// ---------------------------------------------------------------------------
__global__ __launch_bounds__(256) void gemm1_kernel(const float* __restrict__ H,
                                                    const float* __restrict__ X,
                                                    float* __restrict__ C) {
  __shared__ float As[16][68];
  __shared__ float Bs[16][68];
  const int m0 = blockIdx.x * 64;
  const int n0 = blockIdx.y * 64;
  const int tid = threadIdx.x;
  const int lk = tid >> 4;
  const int lm = (tid & 15) << 2;
  const int tm = (tid & 15) << 2;
  const int tn = (tid >> 4) << 2;
  float acc[4][4] = {};
  for (int k0 = 0; k0 < NCODES; k0 += 16) {
    float4 av = *(const float4*)(H + (size_t)(k0 + lk) * T_STEPS + m0 + lm);
    float4 bv = *(const float4*)(X + (size_t)(k0 + lk) * HD + n0 + lm);
    __syncthreads();
    *(float4*)(&As[lk][lm]) = av;
    *(float4*)(&Bs[lk][lm]) = bv;
    __syncthreads();
#pragma unroll
    for (int kk = 0; kk < 16; ++kk) {
      float4 a = *(const float4*)(&As[kk][tm]);
      float4 b = *(const float4*)(&Bs[kk][tn]);
      float ar[4] = {a.x, a.y, a.z, a.w};
      float br[4] = {b.x, b.y, b.z, b.w};
#pragma unroll
      for (int i = 0; i < 4; ++i)
#pragma unroll
        for (int j = 0; j < 4; ++j) acc[i][j] += ar[i] * br[j];
    }
  }
#pragma unroll
  for (int i = 0; i < 4; ++i) {
    float4 o = make_float4(acc[i][0], acc[i][1], acc[i][2], acc[i][3]);
    *(float4*)(C + (size_t)(m0 + tm + i) * HD + n0 + tn) = o;
  }
}

// ---------------------------------------------------------------------------
// GEMM2: gi[4096][1536] = visit (4096x512) @ W_ih^T (512x1536) + b_ih
// ---------------------------------------------------------------------------
__global__ __launch_bounds__(256) void gemm2_kernel(const float* __restrict__ A,
                                                    const float* __restrict__ B,
                                                    const float* __restrict__ bias,
                                                    float* __restrict__ Cout) {
  __shared__ float As[16][68];
  __shared__ float Bs[16][68];
  const int m0 = blockIdx.x * 64;
  const int n0 = blockIdx.y * 64;
  const int tid = threadIdx.x;
  const int lr = tid >> 2;
  const int lkq = (tid & 3) << 2;
  const int tm = (tid & 15) << 2;
  const int tn = (tid >> 4) << 2;
  float acc[4][4] = {};
  for (int k0 = 0; k0 < HD; k0 += 16) {
    float4 av = *(const float4*)(A + (size_t)(m0 + lr) * HD + k0 + lkq);
    float4 bv = *(const float4*)(B + (size_t)(n0 + lr) * HD + k0 + lkq);
    __syncthreads();
    As[lkq + 0][lr] = av.x; As[lkq + 1][lr] = av.y;
    As[lkq + 2][lr] = av.z; As[lkq + 3][lr] = av.w;
    Bs[lkq + 0][lr] = bv.x; Bs[lkq + 1][lr] = bv.y;
    Bs[lkq + 2][lr] = bv.z; Bs[lkq + 3][lr] = bv.w;
    __syncthreads();
#pragma unroll
    for (int kk = 0; kk < 16; ++kk) {
      float4 a = *(const float4*)(&As[kk][tm]);
      float4 b = *(const float4*)(&Bs[kk][tn]);
      float ar[4] = {a.x, a.y, a.z, a.w};
      float br[4] = {b.x, b.y, b.z, b.w};
#pragma unroll
      for (int i = 0; i < 4; ++i)
#pragma unroll
        for (int j = 0; j < 4; ++j) acc[i][j] += ar[i] * br[j];
    }
  }
  const float b0 = bias[n0 + tn + 0];
  const float b1 = bias[n0 + tn + 1];
  const float b2 = bias[n0 + tn + 2];
  const float b3 = bias[n0 + tn + 3];
#pragma unroll
  for (int i = 0; i < 4; ++i) {
    float4 o = make_float4(acc[i][0] + b0, acc[i][1] + b1, acc[i][2] + b2, acc[i][3] + b3);
    *(float4*)(Cout + (size_t)(m0 + tm + i) * G3HD + n0 + tn) = o;
  }
}

// ---------------------------------------------------------------------------
// Persistent GRU scan. XCD-pinned team of 16 WGs x 512 thr (baseline-proven
// topology + sentinel-in-data protocol, NO fences). New: transport through
// the XCD-shared L2 instead of the Infinity Cache.
//   producer: gate lanes (tid<32 of WG g, element e=32g+j) do a PLAIN
//     global_store_dword (write-through vL1 -> shared L2) AND mirror it with
//     a relaxed-agent (sc1, IF$) store -- dual transport, same value.
//   consumer: wave0 lane l polls h[8l..8l+8) with 2x global_load_dwordx4 sc0
//     (SE scope: bypass per-CU L1, served by the shared L2, ~200cy RTT) in
//     ONE asm block incl. s_waitcnt. If a lane spins >16 sweeps it falls
//     back to the baseline relaxed-agent u64 sweep (IF$) -- so a wrong sc0
//     model degrades to ~baseline speed instead of hanging.
// Per step: poll+scatter to hT2 -> B1 -> 8-wave matvec (3 rows x 32k/lane,
// 48 pk-fma) -> 1 shfl_xor(32) -> part LDS -> B2 -> 32 gate lanes sum 8
// partials/gate, gates, dual-store. gi staged in LDS 64 steps ahead; logits
// moved to a downstream kernel.
// ---------------------------------------------------------------------------
__global__ __launch_bounds__(512, 1) void scan_kernel(const float* __restrict__ gi,
                                                      const float* __restrict__ W_hh,
                                                      const float* __restrict__ b_hh,
                                                      float* __restrict__ hs,
                                                      int* __restrict__ ctrl) {
  __shared__ int s_role;
  __shared__ __align__(16) float gibuf[2][64][96];  // [buf][step&63][gate*32+elem]
  __shared__ v2f hT2[256];                          // pair P at [(P&3)*64 + (P>>2)]
  __shared__ float part[8][3][32];                  // [wave][gate][elem]
  const int tid = threadIdx.x;

  if (tid == 0) {
    int xcd;
    asm volatile("s_getreg_b32 %0, hwreg(HW_REG_XCC_ID)" : "=s"(xcd));
    int role = -1;
    const int slot = atomicAdd(&ctrl[xcd], 1);
    if (slot < NWG) {
      if (slot == NWG - 1) atomicCAS(&ctrl[8], -1, xcd);
      int wnr;
      while ((wnr = __hip_atomic_load(&ctrl[8], __ATOMIC_RELAXED,
                                      __HIP_MEMORY_SCOPE_AGENT)) < 0) {
        __builtin_amdgcn_s_sleep(16);
      }
      if (wnr == xcd) role = slot;
    }
    s_role = role;
  }
  __syncthreads();
  const int g = s_role;
  if (g < 0) return;

  const int w = tid >> 6;      // wave 0..7 -> k range [64w, 64w+64)
  const int lane = tid & 63;
  const int e2 = lane & 31;    // element-in-WG 0..31
  const int q = lane >> 5;     // k half -> 32-float chunk
  const int k0 = w * 64 + q * 32;

  // 96 weight floats per lane, register-resident across the whole scan.
  v2f w2[3][16];
#pragma unroll
  for (int r = 0; r < 3; ++r) {
    const v2f* wp = (const v2f*)(W_hh + (size_t)(r * HD + g * 32 + e2) * HD + k0);
#pragma unroll
    for (int j = 0; j < 16; ++j) w2[r][j] = wp[j];
  }
#pragma unroll
  for (int r = 0; r < 3; ++r)
#pragma unroll
    for (int j = 0; j < 16; ++j) asm volatile("" : "+v"(w2[r][j]));

  float bh_r = 0.f, bh_z = 0.f, bh_n = 0.f, hprev = 0.f;
  if (tid < 32) {
    const int ej = g * 32 + tid;
    bh_r = b_hh[ej];
    bh_z = b_hh[HD + ej];
    bh_n = b_hh[2 * HD + ej];
  }

  unsigned* hs_u = (unsigned*)hs;

  // Prologue: stage gi rows 0..63 into gibuf[0].
  uint4v st[3];
#pragma unroll
  for (int j = 0; j < 3; ++j) {
    const int c = tid + 512 * j, row = c / 24, seg = c % 24;
    st[j] = *(const uint4v*)(gi + (size_t)row * G3HD + (seg >> 3) * HD + g * 32 + (seg & 7) * 4);
  }
#pragma unroll
  for (int j = 0; j < 3; ++j) {
    const int c = tid + 512 * j, row = c / 24, seg = c % 24;
    *(uint4v*)&gibuf[0][row][(seg >> 3) * 32 + (seg & 7) * 4] = st[j];
  }
  __syncthreads();

  for (int t = 0; t < T_STEPS; ++t) {
    const int cb = (t >> 6) & 1;
    const int ts = t & 63;

    // ---- wave0: obtain h[t-1] (L2 sentinel poll) and scatter into hT2 ----
    if (tid < 64) {
      uint4v lo, hi;
      if (t == 0) {
        lo = (uint4v)(0u);
        hi = (uint4v)(0u);
      } else {
        const unsigned* hp = hs_u + (size_t)(t - 1) * HD + tid * 8;
        bool done = false;
        int spin = 0;
        while (!done) {
          asm volatile(
              "global_load_dwordx4 %0, %2, off sc0\n\t"
              "global_load_dwordx4 %1, %2, off offset:16 sc0\n\t"
              "s_waitcnt vmcnt(0)"
              : "=&v"(lo), "=&v"(hi)
              : "v"(hp)
              : "memory");
          done = (lo.x != SENT) & (lo.y != SENT) & (lo.z != SENT) & (lo.w != SENT) &
                 (hi.x != SENT) & (hi.y != SENT) & (hi.z != SENT) & (hi.w != SENT);
          if (!done && ++spin >= 16) {  // insurance: baseline IF$ transport
            spin = 0;
            const unsigned long long* p64 = (const unsigned long long*)hp;
            unsigned long long u[4];
#pragma unroll
            for (int m = 0; m < 4; ++m)
              u[m] = __hip_atomic_load(p64 + m, __ATOMIC_RELAXED, __HIP_MEMORY_SCOPE_AGENT);
            bool ok = true;
#pragma unroll
            for (int m = 0; m < 4; ++m)
              ok &= ((unsigned)u[m] != SENT) & ((unsigned)(u[m] >> 32) != SENT);
            if (ok) {
              lo.x = (unsigned)u[0]; lo.y = (unsigned)(u[0] >> 32);
              lo.z = (unsigned)u[1]; lo.w = (unsigned)(u[1] >> 32);
              hi.x = (unsigned)u[2]; hi.y = (unsigned)(u[2] >> 32);
              hi.z = (unsigned)u[3]; hi.w = (unsigned)(u[3] >> 32);
              done = true;
            }
          }
        }
      }
      v2f p0, p1, p2, p3;
      p0.x = __uint_as_float(lo.x); p0.y = __uint_as_float(lo.y);
      p1.x = __uint_as_float(lo.z); p1.y = __uint_as_float(lo.w);
      p2.x = __uint_as_float(hi.x); p2.y = __uint_as_float(hi.y);
      p3.x = __uint_as_float(hi.z); p3.y = __uint_as_float(hi.w);
      hT2[0 * 64 + tid] = p0;
      hT2[1 * 64 + tid] = p1;
      hT2[2 * 64 + tid] = p2;
      hT2[3 * 64 + tid] = p3;
    }
    __syncthreads();  // B1: hT2 ready

    // ---- matvec: 3 rows x 32 k per lane, 48 v_pk_fma_f32 ----
    const int hbase = w * 8 + q * 4;
    v2f h2[16];
#pragma unroll
    for (int m = 0; m < 16; ++m) h2[m] = hT2[(m & 3) * 64 + hbase + (m >> 2)];
    v2f a0 = (v2f)(0.f), a1 = (v2f)(0.f), a2 = (v2f)(0.f);
#pragma unroll
    for (int m = 0; m < 16; ++m) {
      a0 = __builtin_elementwise_fma(w2[0][m], h2[m], a0);
      a1 = __builtin_elementwise_fma(w2[1][m], h2[m], a1);
      a2 = __builtin_elementwise_fma(w2[2][m], h2[m], a2);
    }
    float s0 = a0.x + a0.y;
    float s1 = a1.x + a1.y;
    float s2 = a2.x + a2.y;
    s0 += __shfl_xor(s0, 32);
    s1 += __shfl_xor(s1, 32);
    s2 += __shfl_xor(s2, 32);
    if (q == 0) {
      part[w][0][e2] = s0;
      part[w][1][e2] = s1;
      part[w][2][e2] = s2;
    }

    // ---- gi staging: issue next block at ts==0, LDS-write it at ts==1 ----
    if (ts == 0 && t + 64 < T_STEPS) {
#pragma unroll
      for (int j = 0; j < 3; ++j) {
        const int c = tid + 512 * j, row = c / 24, seg = c % 24;
        st[j] = *(const uint4v*)(gi + (size_t)(t + 64 + row) * G3HD + (seg >> 3) * HD +
                                 g * 32 + (seg & 7) * 4);
      }
    }
    if (ts == 1 && t + 63 < T_STEPS) {
#pragma unroll
      for (int j = 0; j < 3; ++j) {
        const int c = tid + 512 * j, row = c / 24, seg = c % 24;
        *(uint4v*)&gibuf[cb ^ 1][row][(seg >> 3) * 32 + (seg & 7) * 4] = st[j];
      }
    }
    __syncthreads();  // B2: partials ready

    // ---- gates on 32 lanes of wave0; dual-transport store ----
    if (tid < 32) {
      float xr = 0.f, xz = 0.f, xn = 0.f;
#pragma unroll
      for (int ww = 0; ww < 8; ++ww) {
        xr += part[ww][0][tid];
        xz += part[ww][1][tid];
        xn += part[ww][2][tid];
      }
      const float gir = gibuf[cb][ts][tid];
      const float giz = gibuf[cb][ts][32 + tid];
      const float gin = gibuf[cb][ts][64 + tid];
      xr += gir + bh_r;
      xz += giz + bh_z;
      const float ghn = xn + bh_n;
      const float rr = __builtin_amdgcn_rcpf(1.f + __expf(-xr));
      const float zz = __builtin_amdgcn_rcpf(1.f + __expf(-xz));
      const float y = gin + rr * ghn;
      const float nn = 1.f - 2.f * __builtin_amdgcn_rcpf(__expf(2.f * y) + 1.f);
      const float hnew = nn + zz * (hprev - nn);
      unsigned* addr = hs_u + (size_t)t * HD + g * 32 + tid;
      const unsigned uval = __float_as_uint(hnew);
      asm volatile("global_store_dword %0, %1, off" ::"v"(addr), "v"(uval) : "memory");
      __hip_atomic_store(addr, uval, __ATOMIC_RELAXED, __HIP_MEMORY_SCOPE_AGENT);
      hprev = hnew;
    }
  }
}

// ---------------------------------------------------------------------------
// logits[t] = hs[t] . w_att   (off the scan critical path)
// ---------------------------------------------------------------------------
__global__ __launch_bounds__(256) void logits_kernel(const float* __restrict__ hs,
                                                     const float* __restrict__ w_att,
                                                     float* __restrict__ logits) {
  const int tid = threadIdx.x;
  const int r = blockIdx.x * 32 + (tid >> 3);
  const int c0 = (tid & 7) * 64;
  const float4* hp = (const float4*)(hs + (size_t)r * HD + c0);
  const float4* wp = (const float4*)(w_att + c0);
  float acc = 0.f;
#pragma unroll
  for (int i = 0; i < 16; ++i) {
    float4 h4 = hp[i], w4 = wp[i];
    acc += h4.x * w4.x + h4.y * w4.y + h4.z * w4.z + h4.w * w4.w;
  }
  acc += __shfl_xor(acc, 1);
  acc += __shfl_xor(acc, 2);
  acc += __shfl_xor(acc, 4);
  if ((tid & 7) == 0) logits[r] = acc;
}

// ---------------------------------------------------------------------------
// Softmax over 4096 logits, write alpha; zero out.
// ---------------------------------------------------------------------------
__global__ __launch_bounds__(256) void softmax_kernel(const float* __restrict__ logits,
                                                      float* __restrict__ alpha,
                                                      float* __restrict__ out) {
  __shared__ float tmp[4];
  const int tid = threadIdx.x;
  float l[16];
  float m = -1e30f;
#pragma unroll
  for (int i = 0; i < 16; ++i) {
    l[i] = logits[i * 256 + tid];
    m = fmaxf(m, l[i]);
  }
#pragma unroll
  for (int o = 32; o > 0; o >>= 1) m = fmaxf(m, __shfl_xor(m, o));
  if ((tid & 63) == 0) tmp[tid >> 6] = m;
  __syncthreads();
  m = fmaxf(fmaxf(tmp[0], tmp[1]), fmaxf(tmp[2], tmp[3]));
  __syncthreads();
  float e[16];
  float s = 0.f;
#pragma unroll
  for (int i = 0; i < 16; ++i) {
    e[i] = expf(l[i] - m);
    s += e[i];
  }
#pragma unroll
  for (int o = 32; o > 0; o >>= 1) s += __shfl_xor(s, o);
  if ((tid & 63) == 0) tmp[tid >> 6] = s;
  __syncthreads();
  s = tmp[0] + tmp[1] + tmp[2] + tmp[3];
  const float inv = 1.f / s;
#pragma unroll
  for (int i = 0; i < 16; ++i) alpha[i * 256 + tid] = e[i] * inv;
  out[tid] = 0.f;
  out[256 + tid] = 0.f;
}

// ---------------------------------------------------------------------------
// out[j] = sum_t alpha[t] * hs[t][j].  128 WGs: 2 j-halves x 64 t-chunks.
// ---------------------------------------------------------------------------
__global__ __launch_bounds__(256) void wsum_kernel(const float* __restrict__ alpha,
                                                   const float* __restrict__ hs,
                                                   float* __restrict__ out) {
  const int tid = threadIdx.x;
  const int jblk = (blockIdx.x & 1) * 256;
  const int tc = blockIdx.x >> 1;
  float acc = 0.f;
  for (int tt = 0; tt < 64; ++tt) {
    const int t = tc * 64 + tt;
    acc += alpha[t] * hs[(size_t)t * HD + jblk + tid];
  }
  atomicAdd(&out[jblk + tid], acc);
}

extern "C" void kernel_launch(void* const* d_in, const int* in_sizes, int n_in,
                              void* d_out, int out_size, void* d_ws, size_t ws_size,
                              hipStream_t stream) {
  const float* H     = (const float*)d_in[0];
  // d_in[1] = TE, unused by the reference
  const float* X_emb = (const float*)d_in[2];
  const float* W_ih  = (const float*)d_in[3];
  const float* W_hh  = (const float*)d_in[4];
  const float* b_ih  = (const float*)d_in[5];
  const float* b_hh  = (const float*)d_in[6];
  const float* w_att = (const float*)d_in[7];
  float* out = (float*)d_out;

  char* ws = (char*)d_ws;
  float* visit  = (float*)(ws + 0);          //  8 MB: 4096x512
  float* gi     = (float*)(ws + 8388608);    // 25 MB: 4096x1536
  float* hs     = (float*)(ws + 33554432);   //  8 MB: 4096x512
  float* logits = (float*)(ws + 41943040);   // 16 KB: 4096
  float* alpha  = (float*)(ws + 41959424);   // 16 KB
  int*   ctrl   = (int*)(ws + 41975808);     // [0..7] per-XCD counters, [8] winner

  // sentinel-fill hs (0xFFFFFFFF = -NaN, unreachable from finite GRU math)
  hipMemsetAsync(hs, 0xFF, (size_t)T_STEPS * HD * sizeof(float), stream);
  hipMemsetAsync(ctrl, 0, 8 * sizeof(int), stream);
  hipMemsetAsync(ctrl + 8, 0xFF, sizeof(int), stream);  // winner = -1

  gemm1_kernel<<<dim3(64, 8), 256, 0, stream>>>(H, X_emb, visit);
  gemm2_kernel<<<dim3(64, 24), 256, 0, stream>>>(visit, W_ih, b_ih, gi);
  scan_kernel<<<256, 512, 0, stream>>>(gi, W_hh, b_hh, hs, ctrl);
  logits_kernel<<<128, 256, 0, stream>>>(hs, w_att, logits);
  softmax_kernel<<<1, 256, 0, stream>>>(logits, alpha, out);
  wsum_kernel<<<128, 256, 0, stream>>>(alpha, hs, out);
}

// Round 5
// 5558.453 us; speedup vs baseline: 10.0075x; 2.8045x over previous
//
#include <hip/hip_runtime.h>

#define T_STEPS 4096
#define HD 512
#define G3HD 1536
#define NCODES 4880
#define NWG 16
#define SENT 0xFFFFFFFFu

typedef __attribute__((ext_vector_type(2))) float v2f;
typedef __attribute__((ext_vector_type(4))) unsigned uint4v;

// ---------------------------------------------------------------------------
// GEMM1: visit[4096][512] = H^T (4096x4880) @ X_emb (4880x512)
// ---------------------------------------------------------------------------
__global__ __launch_bounds__(256) void gemm1_kernel(const float* __restrict__ H,
                                                    const float* __restrict__ X,
                                                    float* __restrict__ C) {
  __shared__ float As[16][68];
  __shared__ float Bs[16][68];
  const int m0 = blockIdx.x * 64;
  const int n0 = blockIdx.y * 64;
  const int tid = threadIdx.x;
  const int lk = tid >> 4;
  const int lm = (tid & 15) << 2;
  const int tm = (tid & 15) << 2;
  const int tn = (tid >> 4) << 2;
  float acc[4][4] = {};
  for (int k0 = 0; k0 < NCODES; k0 += 16) {
    float4 av = *(const float4*)(H + (size_t)(k0 + lk) * T_STEPS + m0 + lm);
    float4 bv = *(const float4*)(X + (size_t)(k0 + lk) * HD + n0 + lm);
    __syncthreads();
    *(float4*)(&As[lk][lm]) = av;
    *(float4*)(&Bs[lk][lm]) = bv;
    __syncthreads();
#pragma unroll
    for (int kk = 0; kk < 16; ++kk) {
      float4 a = *(const float4*)(&As[kk][tm]);
      float4 b = *(const float4*)(&Bs[kk][tn]);
      float ar[4] = {a.x, a.y, a.z, a.w};
      float br[4] = {b.x, b.y, b.z, b.w};
#pragma unroll
      for (int i = 0; i < 4; ++i)
#pragma unroll
        for (int j = 0; j < 4; ++j) acc[i][j] += ar[i] * br[j];
    }
  }
#pragma unroll
  for (int i = 0; i < 4; ++i) {
    float4 o = make_float4(acc[i][0], acc[i][1], acc[i][2], acc[i][3]);
    *(float4*)(C + (size_t)(m0 + tm + i) * HD + n0 + tn) = o;
  }
}

// ---------------------------------------------------------------------------
// GEMM2: gi[4096][1536] = visit (4096x512) @ W_ih^T (512x1536) + b_ih
// ---------------------------------------------------------------------------
__global__ __launch_bounds__(256) void gemm2_kernel(const float* __restrict__ A,
                                                    const float* __restrict__ B,
                                                    const float* __restrict__ bias,
                                                    float* __restrict__ Cout) {
  __shared__ float As[16][68];
  __shared__ float Bs[16][68];
  const int m0 = blockIdx.x * 64;
  const int n0 = blockIdx.y * 64;
  const int tid = threadIdx.x;
  const int lr = tid >> 2;
  const int lkq = (tid & 3) << 2;
  const int tm = (tid & 15) << 2;
  const int tn = (tid >> 4) << 2;
  float acc[4][4] = {};
  for (int k0 = 0; k0 < HD; k0 += 16) {
    float4 av = *(const float4*)(A + (size_t)(m0 + lr) * HD + k0 + lkq);
    float4 bv = *(const float4*)(B + (size_t)(n0 + lr) * HD + k0 + lkq);
    __syncthreads();
    As[lkq + 0][lr] = av.x; As[lkq + 1][lr] = av.y;
    As[lkq + 2][lr] = av.z; As[lkq + 3][lr] = av.w;
    Bs[lkq + 0][lr] = bv.x; Bs[lkq + 1][lr] = bv.y;
    Bs[lkq + 2][lr] = bv.z; Bs[lkq + 3][lr] = bv.w;
    __syncthreads();
#pragma unroll
    for (int kk = 0; kk < 16; ++kk) {
      float4 a = *(const float4*)(&As[kk][tm]);
      float4 b = *(const float4*)(&Bs[kk][tn]);
      float ar[4] = {a.x, a.y, a.z, a.w};
      float br[4] = {b.x, b.y, b.z, b.w};
#pragma unroll
      for (int i = 0; i < 4; ++i)
#pragma unroll
        for (int j = 0; j < 4; ++j) acc[i][j] += ar[i] * br[j];
    }
  }
  const float b0 = bias[n0 + tn + 0];
  const float b1 = bias[n0 + tn + 1];
  const float b2 = bias[n0 + tn + 2];
  const float b3 = bias[n0 + tn + 3];
#pragma unroll
  for (int i = 0; i < 4; ++i) {
    float4 o = make_float4(acc[i][0] + b0, acc[i][1] + b1, acc[i][2] + b2, acc[i][3] + b3);
    *(float4*)(Cout + (size_t)(m0 + tm + i) * G3HD + n0 + tn) = o;
  }
}

// ---------------------------------------------------------------------------
// Persistent GRU scan. XCD-pinned team of 16 WGs x 512 thr. BASELINE-proven
// transport (relaxed-agent atomics + sentinel-in-data, NO fences, no asm in
// the exchange). Change vs baseline: the poll is distributed -- EACH of the
// 512 threads polls exactly ONE dword h[t-1][tid] with ONE atomic load per
// sweep (round-0/2 evidence: agent atomic loads serialize at ~560cy each, so
// baseline's 4-load sweep paid 4 RTTs; this pays 1), writes it to hT[tid],
// B1. Matvec: lane (w,q,e2) owns rows {e,512+e,1024+e}, e=32g+e2, k in
// [64w+32q,+32): 16 broadcast LDS v2f reads + 48 v_pk_fma. 1-level
// shfl_xor(32) reduce + part LDS, B2, gates on 32 lanes, SINGLE relaxed-agent
// store. gi bulk-staged to LDS 64 steps ahead; logits downstream.
// ---------------------------------------------------------------------------
__global__ __launch_bounds__(512, 1) void scan_kernel(const float* __restrict__ gi,
                                                      const float* __restrict__ W_hh,
                                                      const float* __restrict__ b_hh,
                                                      float* __restrict__ hs,
                                                      int* __restrict__ ctrl) {
  __shared__ int s_role;
  __shared__ __align__(16) float gibuf[2][64][96];  // [buf][step&63][gate*32+elem]
  __shared__ __align__(16) float hT[HD];            // h[t-1], linear
  __shared__ float part[8][3][32];                  // [wave][gate][elem]
  const int tid = threadIdx.x;

  if (tid == 0) {
    int xcd;
    asm volatile("s_getreg_b32 %0, hwreg(HW_REG_XCC_ID)" : "=s"(xcd));
    int role = -1;
    const int slot = atomicAdd(&ctrl[xcd], 1);
    if (slot < NWG) {
      if (slot == NWG - 1) atomicCAS(&ctrl[8], -1, xcd);
      int wnr;
      while ((wnr = __hip_atomic_load(&ctrl[8], __ATOMIC_RELAXED,
                                      __HIP_MEMORY_SCOPE_AGENT)) < 0) {
        __builtin_amdgcn_s_sleep(16);
      }
      if (wnr == xcd) role = slot;
    }
    s_role = role;
  }
  __syncthreads();
  const int g = s_role;
  if (g < 0) return;

  const int w = tid >> 6;      // wave 0..7 -> k range [64w, 64w+64)
  const int lane = tid & 63;
  const int e2 = lane & 31;    // element-in-WG 0..31
  const int q = lane >> 5;     // k half -> 32-float chunk
  const int k0 = w * 64 + q * 32;

  // 96 weight floats per lane, register-resident across the whole scan.
  v2f w2[3][16];
#pragma unroll
  for (int r = 0; r < 3; ++r) {
    const v2f* wp = (const v2f*)(W_hh + (size_t)(r * HD + g * 32 + e2) * HD + k0);
#pragma unroll
    for (int j = 0; j < 16; ++j) w2[r][j] = wp[j];
  }
#pragma unroll
  for (int r = 0; r < 3; ++r)
#pragma unroll
    for (int j = 0; j < 16; ++j) asm volatile("" : "+v"(w2[r][j]));

  float bh_r = 0.f, bh_z = 0.f, bh_n = 0.f, hprev = 0.f;
  if (tid < 32) {
    const int ej = g * 32 + tid;
    bh_r = b_hh[ej];
    bh_z = b_hh[HD + ej];
    bh_n = b_hh[2 * HD + ej];
  }

  unsigned* hs_u = (unsigned*)hs;

  // Prologue: stage gi rows 0..63 into gibuf[0].
  uint4v st[3];
#pragma unroll
  for (int j = 0; j < 3; ++j) {
    const int c = tid + 512 * j, row = c / 24, seg = c % 24;
    st[j] = *(const uint4v*)(gi + (size_t)row * G3HD + (seg >> 3) * HD + g * 32 + (seg & 7) * 4);
  }
#pragma unroll
  for (int j = 0; j < 3; ++j) {
    const int c = tid + 512 * j, row = c / 24, seg = c % 24;
    *(uint4v*)&gibuf[0][row][(seg >> 3) * 32 + (seg & 7) * 4] = st[j];
  }
  __syncthreads();

  for (int t = 0; t < T_STEPS; ++t) {
    const int cb = (t >> 6) & 1;
    const int ts = t & 63;

    // ---- each thread polls its OWN single dword of h[t-1]: 1 RTT/sweep ----
    if (t == 0) {
      hT[tid] = 0.f;  // h(-1) = 0
    } else {
      const unsigned* hp = hs_u + (size_t)(t - 1) * HD + tid;
      unsigned v = __hip_atomic_load(hp, __ATOMIC_RELAXED, __HIP_MEMORY_SCOPE_AGENT);
      while (v == SENT)
        v = __hip_atomic_load(hp, __ATOMIC_RELAXED, __HIP_MEMORY_SCOPE_AGENT);
      hT[tid] = __uint_as_float(v);
    }
    __syncthreads();  // B1: hT ready

    // ---- matvec: 3 rows x 32 k per lane, 48 v_pk_fma_f32 (broadcast LDS) ----
    const v2f* hv = (const v2f*)&hT[k0];
    v2f h2[16];
#pragma unroll
    for (int m = 0; m < 16; ++m) h2[m] = hv[m];
    v2f a0 = (v2f)(0.f), a1 = (v2f)(0.f), a2 = (v2f)(0.f);
#pragma unroll
    for (int m = 0; m < 16; ++m) {
      a0 = __builtin_elementwise_fma(w2[0][m], h2[m], a0);
      a1 = __builtin_elementwise_fma(w2[1][m], h2[m], a1);
      a2 = __builtin_elementwise_fma(w2[2][m], h2[m], a2);
    }
    float s0 = a0.x + a0.y;
    float s1 = a1.x + a1.y;
    float s2 = a2.x + a2.y;
    s0 += __shfl_xor(s0, 32);
    s1 += __shfl_xor(s1, 32);
    s2 += __shfl_xor(s2, 32);
    if (q == 0) {
      part[w][0][e2] = s0;
      part[w][1][e2] = s1;
      part[w][2][e2] = s2;
    }

    // ---- gi staging: issue next block at ts==0, LDS-write it at ts==1 ----
    if (ts == 0 && t + 64 < T_STEPS) {
#pragma unroll
      for (int j = 0; j < 3; ++j) {
        const int c = tid + 512 * j, row = c / 24, seg = c % 24;
        st[j] = *(const uint4v*)(gi + (size_t)(t + 64 + row) * G3HD + (seg >> 3) * HD +
                                 g * 32 + (seg & 7) * 4);
      }
    }
    if (ts == 1 && t + 63 < T_STEPS) {
#pragma unroll
      for (int j = 0; j < 3; ++j) {
        const int c = tid + 512 * j, row = c / 24, seg = c % 24;
        *(uint4v*)&gibuf[cb ^ 1][row][(seg >> 3) * 32 + (seg & 7) * 4] = st[j];
      }
    }
    __syncthreads();  // B2: partials ready

    // ---- gates on 32 lanes of wave0; single relaxed-agent store ----
    if (tid < 32) {
      float xr = 0.f, xz = 0.f, xn = 0.f;
#pragma unroll
      for (int ww = 0; ww < 8; ++ww) {
        xr += part[ww][0][tid];
        xz += part[ww][1][tid];
        xn += part[ww][2][tid];
      }
      const float gir = gibuf[cb][ts][tid];
      const float giz = gibuf[cb][ts][32 + tid];
      const float gin = gibuf[cb][ts][64 + tid];
      xr += gir + bh_r;
      xz += giz + bh_z;
      const float ghn = xn + bh_n;
      const float rr = __builtin_amdgcn_rcpf(1.f + __expf(-xr));
      const float zz = __builtin_amdgcn_rcpf(1.f + __expf(-xz));
      const float y = gin + rr * ghn;
      const float nn = 1.f - 2.f * __builtin_amdgcn_rcpf(__expf(2.f * y) + 1.f);
      const float hnew = nn + zz * (hprev - nn);
      __hip_atomic_store(hs_u + (size_t)t * HD + g * 32 + tid, __float_as_uint(hnew),
                         __ATOMIC_RELAXED, __HIP_MEMORY_SCOPE_AGENT);
      hprev = hnew;
    }
  }
}

// ---------------------------------------------------------------------------
// logits[t] = hs[t] . w_att   (off the scan critical path)
// ---------------------------------------------------------------------------
__global__ __launch_bounds__(256) void logits_kernel(const float* __restrict__ hs,
                                                     const float* __restrict__ w_att,
                                                     float* __restrict__ logits) {
  const int tid = threadIdx.x;
  const int r = blockIdx.x * 32 + (tid >> 3);
  const int c0 = (tid & 7) * 64;
  const float4* hp = (const float4*)(hs + (size_t)r * HD + c0);
  const float4* wp = (const float4*)(w_att + c0);
  float acc = 0.f;
#pragma unroll
  for (int i = 0; i < 16; ++i) {
    float4 h4 = hp[i], w4 = wp[i];
    acc += h4.x * w4.x + h4.y * w4.y + h4.z * w4.z + h4.w * w4.w;
  }
  acc += __shfl_xor(acc, 1);
  acc += __shfl_xor(acc, 2);
  acc += __shfl_xor(acc, 4);
  if ((tid & 7) == 0) logits[r] = acc;
}

// ---------------------------------------------------------------------------
// Softmax over 4096 logits, write alpha; zero out.
// ---------------------------------------------------------------------------
__global__ __launch_bounds__(256) void softmax_kernel(const float* __restrict__ logits,
                                                      float* __restrict__ alpha,
                                                      float* __restrict__ out) {
  __shared__ float tmp[4];
  const int tid = threadIdx.x;
  float l[16];
  float m = -1e30f;
#pragma unroll
  for (int i = 0; i < 16; ++i) {
    l[i] = logits[i * 256 + tid];
    m = fmaxf(m, l[i]);
  }
#pragma unroll
  for (int o = 32; o > 0; o >>= 1) m = fmaxf(m, __shfl_xor(m, o));
  if ((tid & 63) == 0) tmp[tid >> 6] = m;
  __syncthreads();
  m = fmaxf(fmaxf(tmp[0], tmp[1]), fmaxf(tmp[2], tmp[3]));
  __syncthreads();
  float e[16];
  float s = 0.f;
#pragma unroll
  for (int i = 0; i < 16; ++i) {
    e[i] = expf(l[i] - m);
    s += e[i];
  }
#pragma unroll
  for (int o = 32; o > 0; o >>= 1) s += __shfl_xor(s, o);
  if ((tid & 63) == 0) tmp[tid >> 6] = s;
  __syncthreads();
  s = tmp[0] + tmp[1] + tmp[2] + tmp[3];
  const float inv = 1.f / s;
#pragma unroll
  for (int i = 0; i < 16; ++i) alpha[i * 256 + tid] = e[i] * inv;
  out[tid] = 0.f;
  out[256 + tid] = 0.f;
}

// ---------------------------------------------------------------------------
// out[j] = sum_t alpha[t] * hs[t][j].  128 WGs: 2 j-halves x 64 t-chunks.
// ---------------------------------------------------------------------------
__global__ __launch_bounds__(256) void wsum_kernel(const float* __restrict__ alpha,
                                                   const float* __restrict__ hs,
                                                   float* __restrict__ out) {
  const int tid = threadIdx.x;
  const int jblk = (blockIdx.x & 1) * 256;
  const int tc = blockIdx.x >> 1;
  float acc = 0.f;
  for (int tt = 0; tt < 64; ++tt) {
    const int t = tc * 64 + tt;
    acc += alpha[t] * hs[(size_t)t * HD + jblk + tid];
  }
  atomicAdd(&out[jblk + tid], acc);
}

extern "C" void kernel_launch(void* const* d_in, const int* in_sizes, int n_in,
                              void* d_out, int out_size, void* d_ws, size_t ws_size,
                              hipStream_t stream) {
  const float* H     = (const float*)d_in[0];
  // d_in[1] = TE, unused by the reference
  const float* X_emb = (const float*)d_in[2];
  const float* W_ih  = (const float*)d_in[3];
  const float* W_hh  = (const float*)d_in[4];
  const float* b_ih  = (const float*)d_in[5];
  const float* b_hh  = (const float*)d_in[6];
  const float* w_att = (const float*)d_in[7];
  float* out = (float*)d_out;

  char* ws = (char*)d_ws;
  float* visit  = (float*)(ws + 0);          //  8 MB: 4096x512
  float* gi     = (float*)(ws + 8388608);    // 25 MB: 4096x1536
  float* hs     = (float*)(ws + 33554432);   //  8 MB: 4096x512
  float* logits = (float*)(ws + 41943040);   // 16 KB: 4096
  float* alpha  = (float*)(ws + 41959424);   // 16 KB
  int*   ctrl   = (int*)(ws + 41975808);     // [0..7] per-XCD counters, [8] winner

  // sentinel-fill hs (0xFFFFFFFF = -NaN, unreachable from finite GRU math)
  hipMemsetAsync(hs, 0xFF, (size_t)T_STEPS * HD * sizeof(float), stream);
  hipMemsetAsync(ctrl, 0, 8 * sizeof(int), stream);
  hipMemsetAsync(ctrl + 8, 0xFF, sizeof(int), stream);  // winner = -1

  gemm1_kernel<<<dim3(64, 8), 256, 0, stream>>>(H, X_emb, visit);
  gemm2_kernel<<<dim3(64, 24), 256, 0, stream>>>(visit, W_ih, b_ih, gi);
  scan_kernel<<<256, 512, 0, stream>>>(gi, W_hh, b_hh, hs, ctrl);
  logits_kernel<<<128, 256, 0, stream>>>(hs, w_att, logits);
  softmax_kernel<<<1, 256, 0, stream>>>(logits, alpha, out);
  wsum_kernel<<<128, 256, 0, stream>>>(alpha, hs, out);
}